// Round 1
// baseline (2909.380 us; speedup 1.0000x reference)
//
#include <hip/hip_runtime.h>

namespace {

constexpr int SZi   = 4096;
constexpr int NPIX  = SZi * SZi;          // 16777216
constexpr int BLK   = 256;
constexpr int BPC   = NPIX / BLK;         // 65536 blocks per channel

// Filled-pixel flat positions (row-major nonzero enumeration of each mask).
__device__ __forceinline__ int posR(int f) {
    // (2i)*4096 + 2j ; i=f>>11, j=f&2047
    return ((f >> 11) << 13) | ((f & 2047) << 1);
}
__device__ __forceinline__ int posB(int f) {
    // (2i+1)*4096 + 2j+1
    return ((f >> 11) << 13) | 4096 | ((f & 2047) << 1) | 1;
}
__device__ __forceinline__ int posG(int f) {
    // row rr=f>>11; col = 2*jj+1 if rr even else 2*jj
    const int rr = f >> 11;
    return (rr << 12) | ((f & 2047) << 1) | ((rr & 1) ^ 1);
}

__device__ __forceinline__ float wavg(const float4 d, float v0, float v1, float v2, float v3) {
    const float num = v0 * d.x + v1 * d.y + v2 * d.z + v3 * d.w;
    const float den = d.x + d.y + d.z + d.w;
    return num / den;
}

__global__ __launch_bounds__(BLK) void demosaic(
    const float*  __restrict__ img,
    const int4*   __restrict__ idx_r, const float4* __restrict__ dist_r,
    const int4*   __restrict__ idx_g, const float4* __restrict__ dist_g,
    const int4*   __restrict__ idx_b, const float4* __restrict__ dist_b,
    float*        __restrict__ out)
{
    const int ch = blockIdx.x >> 16;                       // block-uniform channel
    const int p  = ((blockIdx.x & 0xFFFF) << 8) | threadIdx.x;
    const int r  = p >> 12;
    const int c  = p & 4095;

    float val;
    if (ch == 0) {
        // RED: filled at (even r, even c)
        if (((r | c) & 1) == 0) {
            val = img[p];
        } else {
            const int pr = r >> 1;
            const int u  = (r & 1) ? (pr * 6144 + 2048 + c)     // odd row: all cols unfilled
                                   : (pr * 6144 + (c >> 1));    // even row: odd cols
            const int4   id = idx_r[u];
            const float4 d  = dist_r[u];
            val = wavg(d, img[posR(id.x)], img[posR(id.y)],
                          img[posR(id.z)], img[posR(id.w)]);
        }
    } else if (ch == 1) {
        // GREEN: filled where (r^c) odd
        if (((r ^ c) & 1) != 0) {
            val = img[p];
        } else {
            const int u = (r << 11) | (c >> 1);
            const int4   id = idx_g[u];
            const float4 d  = dist_g[u];
            val = wavg(d, img[posG(id.x)], img[posG(id.y)],
                          img[posG(id.z)], img[posG(id.w)]);
        }
    } else {
        // BLUE: filled at (odd r, odd c)
        if (((r & c) & 1) != 0) {
            val = img[p];
        } else {
            const int pr = r >> 1;
            const int u  = (r & 1) ? (pr * 6144 + 4096 + (c >> 1))  // odd row: even cols
                                   : (pr * 6144 + c);               // even row: all cols
            const int4   id = idx_b[u];
            const float4 d  = dist_b[u];
            val = wavg(d, img[posB(id.x)], img[posB(id.y)],
                          img[posB(id.z)], img[posB(id.w)]);
        }
    }
    out[ch * NPIX + p] = val;
}

} // namespace

extern "C" void kernel_launch(void* const* d_in, const int* in_sizes, int n_in,
                              void* d_out, int out_size, void* d_ws, size_t ws_size,
                              hipStream_t stream) {
    const float*  img    = (const float*)  d_in[0];
    const int4*   idx_r  = (const int4*)   d_in[1];
    const float4* dist_r = (const float4*) d_in[2];
    const int4*   idx_g  = (const int4*)   d_in[3];
    const float4* dist_g = (const float4*) d_in[4];
    const int4*   idx_b  = (const int4*)   d_in[5];
    const float4* dist_b = (const float4*) d_in[6];
    float*        out    = (float*)        d_out;

    dim3 grid(3 * BPC), block(BLK);
    demosaic<<<grid, block, 0, stream>>>(img, idx_r, dist_r, idx_g, dist_g,
                                         idx_b, dist_b, out);
}